// Round 10
// baseline (352.202 us; speedup 1.0000x reference)
//
#include <hip/hip_runtime.h>

#define N_NODES_C 50000
#define FDIM 64
#define EPS_C 1e-5f

#define PARTS 16               // node partitions; 50000/16 = 3125 exact
#define NPP 3125
#define SLICE (3 * NPP)        // accumulate LDS: 9375 floats = 37.5 KB
#define NSHARD 8               // sublists per partition (shard = blockIdx&7)
#define NLIST (PARTS * NSHARD) // 128 sublists
#define SUBCAP 16384           // entries per sublist (16 B) -> 32 MB total
#define BUK_BLK 512
#define BUK_GRID 1024          // 4 blk/CU co-resident (40 KB LDS), 8192 waves
#define CAP 160                // LDS bucket capacity (block mean 98, +6.4 sigma)
#define ACC_BLK 512

typedef float vfloat4 __attribute__((ext_vector_type(4)));

__device__ __forceinline__ void nt_store_f4(float4* p, float x, float y, float z, float w) {
    vfloat4 v = { x, y, z, w };
    __builtin_nontemporal_store(v, (vfloat4*)p);
}

// ---------------------------------------------------------------------------
// Pass 1: bucketize. Streams e once (16 lanes/edge, float4, shfl-reduce);
// group leader appends {local,sum,sq} to an LDS bucket for partition
// dst/NPP; one batched global flush per bucket at kernel end (sharded
// counters -> ~16K device atomics total). dst and e each read exactly once.
// ---------------------------------------------------------------------------
__global__ void __launch_bounds__(BUK_BLK)
bucketize_kernel(const float4* __restrict__ e4, const int* __restrict__ dst,
                 float4* __restrict__ lists, int* __restrict__ gcnt, int nEdges) {
    __shared__ float4 buk[PARTS][CAP];   // 40 KB
    __shared__ int bcnt[PARTS];
    __shared__ int flushbase;
    const int tid = threadIdx.x;
    if (tid < PARTS) bcnt[tid] = 0;
    __syncthreads();

    const int group = tid >> 4, sub = tid & 15;
    const int NG  = BUK_GRID * (BUK_BLK / 16);       // 32768 groups
    const int gid = blockIdx.x * (BUK_BLK / 16) + group;
    const int shard = blockIdx.x & (NSHARD - 1);
    const int R = (nEdges + NG - 1) / NG;            // block-uniform

    for (int r = 0; r < R; ++r) {
        const int edge = gid + r * NG;
        if (edge < nEdges) {
            float4 v = e4[(size_t)edge * 16 + sub];
            float sum = (v.x + v.y) + (v.z + v.w);
            float sq  = (v.x * v.x + v.y * v.y) + (v.z * v.z + v.w * v.w);
#pragma unroll
            for (int m = 1; m < 16; m <<= 1) {
                sum += __shfl_xor(sum, m);
                sq  += __shfl_xor(sq,  m);
            }
            if (sub == 0) {
                int d = dst[edge];
                int p = d / NPP;                      // magic-mul (const div)
                int local = d - p * NPP;
                float4 ent;
                ent.x = __uint_as_float((unsigned)local);
                ent.y = sum; ent.z = sq; ent.w = 0.0f;
                int pos = atomicAdd(&bcnt[p], 1);
                if (pos < CAP) {
                    buk[p][pos] = ent;
                } else {   // freak-overflow spill path (correct, ~never taken)
                    int g = atomicAdd(&gcnt[p * NSHARD + shard], 1);
                    if (g < SUBCAP)
                        lists[(size_t)(p * NSHARD + shard) * SUBCAP + g] = ent;
                }
            }
        }
    }
    __syncthreads();

    // one batched flush per bucket
    for (int q = 0; q < PARTS; ++q) {
        const int c = min(bcnt[q], CAP);              // block-uniform
        if (c > 0) {
            if (tid == 0) flushbase = atomicAdd(&gcnt[q * NSHARD + shard], c);
            __syncthreads();
            const int base = flushbase;
            float4* dstp = lists + (size_t)(q * NSHARD + shard) * SUBCAP;
            for (int i = tid; i < c; i += BUK_BLK)
                if (base + i < SUBCAP) dstp[base + i] = buk[q][i];
        }
        __syncthreads();
    }
}

// ---------------------------------------------------------------------------
// Pass 2: accumulate. One block per sublist: 3 LDS atomics per entry (100%
// in-range), then flush the 37.5 KB partition slice to acc (nt stores).
// ---------------------------------------------------------------------------
__global__ void __launch_bounds__(ACC_BLK)
accumulate_kernel(const float4* __restrict__ lists, const int* __restrict__ gcnt,
                  float* __restrict__ acc) {
    __shared__ float sm[SLICE];
    const int tid = threadIdx.x;
    for (int i = tid; i < SLICE; i += ACC_BLK) sm[i] = 0.0f;
    __syncthreads();

    const int li  = blockIdx.x;                       // p*NSHARD + s
    const int cnt = min(gcnt[li], SUBCAP);
    const float4* src = lists + (size_t)li * SUBCAP;
    for (int i = tid; i < cnt; i += ACC_BLK) {
        float4 ent = src[i];
        unsigned l = __float_as_uint(ent.x);
        atomicAdd(&sm[l], ent.y);
        atomicAdd(&sm[NPP + l], ent.z);
        atomicAdd(&sm[2 * NPP + l], 1.0f);
    }
    __syncthreads();
    float* __restrict__ outp = acc + (size_t)li * SLICE;
    for (int i = tid; i < SLICE; i += ACC_BLK)
        __builtin_nontemporal_store(sm[i], outp + i);
}

// ---------------------------------------------------------------------------
// Pass 3: sum the NSHARD copies per partition; mean + 1/(std+eps), (n-1).
// ---------------------------------------------------------------------------
__global__ void __launch_bounds__(256)
reduce_finalize_kernel(const float* __restrict__ acc, float2* __restrict__ stats,
                       int nNodes) {
    int n = blockIdx.x * blockDim.x + threadIdx.x;
    if (n >= nNodes) return;
    int p = n / NPP, local = n - p * NPP;
    const float* bptr = acc + (size_t)(p * NSHARD) * SLICE + local;
    float s = 0.f, q = 0.f, dg = 0.f;
#pragma unroll
    for (int ss = 0; ss < NSHARD; ++ss, bptr += SLICE) {
        s  += bptr[0];
        q  += bptr[NPP];
        dg += bptr[2 * NPP];
    }
    float cnt  = dg * (float)FDIM;
    float safe = fmaxf(cnt, 1.0f);
    float mean = s / safe;
    float var  = (q - cnt * mean * mean) / fmaxf(cnt - 1.0f, 1.0f);
    float stdv = sqrtf(fmaxf(var, 0.0f));
    stats[n] = make_float2(mean, 1.0f / (stdv + EPS_C));
}

// ---------------------------------------------------------------------------
// Pass 4: normalize. Reverse iteration (read e's L3-resident tail first) +
// nt stores (out's 410 MB must not evict e from L3).
// ---------------------------------------------------------------------------
__global__ void __launch_bounds__(256)
norm_kernel(const float4* __restrict__ e4, const int* __restrict__ dst,
            const float2* __restrict__ stats,
            const float4* __restrict__ gamma4, const float4* __restrict__ beta4,
            float4* __restrict__ out4, int nEdges) {
    const int total  = nEdges * 16;
    const int stride = gridDim.x * blockDim.x;   // %16==0
    const int gtid   = blockIdx.x * blockDim.x + threadIdx.x;
    const int sub    = gtid & 15;
    const float4 g = gamma4[sub];
    const float4 b = beta4[sub];
    const int nIter = (total + stride - 1) / stride;
    for (int it = nIter - 1; it >= 0; --it) {
        int idx = it * stride + gtid;
        if (idx >= total) continue;
        float2 mi = stats[dst[idx >> 4]];
        float4 v  = e4[idx];
        nt_store_f4(out4 + idx,
                    g.x * (v.x - mi.x) * mi.y + b.x,
                    g.y * (v.y - mi.x) * mi.y + b.y,
                    g.z * (v.z - mi.x) * mi.y + b.z,
                    g.w * (v.w - mi.x) * mi.y + b.w);
    }
}

extern "C" void kernel_launch(void* const* d_in, const int* in_sizes, int n_in,
                              void* d_out, int out_size, void* d_ws, size_t ws_size,
                              hipStream_t stream) {
    const float* e     = (const float*)d_in[0];
    const float* gamma = (const float*)d_in[1];
    const float* beta  = (const float*)d_in[2];
    const int*   dst   = (const int*)d_in[3];
    const int nEdges = in_sizes[3];
    const int nNodes = N_NODES_C;

    // d_ws layout:
    //   lists [NLIST][SUBCAP] float4 = 32 MB
    //   acc   [NLIST][SLICE]  float  = 4.8 MB
    //   stats [N] float2              = 0.4 MB
    //   gcnt  [NLIST] int             = 512 B   (memset to 0 each call)
    float4* lists = (float4*)d_ws;
    float*  acc   = (float*)(lists + (size_t)NLIST * SUBCAP);
    float2* stats = (float2*)(acc + (size_t)NLIST * SLICE);
    int*    gcnt  = (int*)(stats + nNodes);

    hipMemsetAsync(gcnt, 0, NLIST * sizeof(int), stream);

    bucketize_kernel<<<BUK_GRID, BUK_BLK, 0, stream>>>(
        (const float4*)e, dst, lists, gcnt, nEdges);
    accumulate_kernel<<<NLIST, ACC_BLK, 0, stream>>>(lists, gcnt, acc);
    reduce_finalize_kernel<<<(nNodes + 255) / 256, 256, 0, stream>>>(acc, stats, nNodes);
    norm_kernel<<<2048, 256, 0, stream>>>(
        (const float4*)e, dst, stats,
        (const float4*)gamma, (const float4*)beta,
        (float4*)d_out, nEdges);
}

// Round 11
// 251.676 us; speedup vs baseline: 1.3994x; 1.3994x over previous
//
#include <hip/hip_runtime.h>

#define N_NODES_C 50000
#define FDIM 64
#define EPS_C 1e-5f

#define PARTS 16            // 50000/16 = 3125 exact
#define NPP 3125
#define SLICE (3 * NPP)     // 9375 floats = 37.5 KB LDS
#define BPERP 48            // grid = 768 = 3 blocks/CU
#define SCAT_BLK 512
#define SCAT_GRID (PARTS * BPERP)

typedef float vfloat4 __attribute__((ext_vector_type(4)));

__device__ __forceinline__ void nt_store_f4(float4* p, float x, float y, float z, float w) {
    vfloat4 v = { x, y, z, w };
    __builtin_nontemporal_store(v, (vfloat4*)p);
}

// one edge: conditional LDS-atomic triple
#define EDGE_ACC(D, SV, QV)                                            \
    { unsigned l_ = (unsigned)((D) - lo);                              \
      if (l_ < NPP) { atomicAdd(&sm[l_], (SV));                        \
                      atomicAdd(&sm[NPP + l_], (QV));                  \
                      atomicAdd(&sm[2 * NPP + l_], 1.0f); } }

// ---------------------------------------------------------------------------
// Pass A: per-edge partials. Pure dense stream of e (normal loads -> e
// allocates in L3 for norm's re-read); nt-store partials (no pollution).
// ---------------------------------------------------------------------------
__global__ void __launch_bounds__(256)
partial_kernel(const float4* __restrict__ e4, float2* __restrict__ partials,
               int nEdges) {
    const int total = nEdges * 16;
    const int stride = gridDim.x * blockDim.x;   // %16==0 -> groups aligned
    for (int idx = blockIdx.x * blockDim.x + threadIdx.x; idx < total; idx += stride) {
        float4 v = e4[idx];
        float sum = (v.x + v.y) + (v.z + v.w);
        float sq  = (v.x * v.x + v.y * v.y) + (v.z * v.z + v.w * v.w);
#pragma unroll
        for (int m = 1; m < 16; m <<= 1) {
            sum += __shfl_xor(sum, m);
            sq  += __shfl_xor(sq,  m);
        }
        if ((idx & 15) == 0) {
            unsigned long long bits;
            float2 pq = make_float2(sum, sq);
            __builtin_memcpy(&bits, &pq, 8);
            __builtin_nontemporal_store(bits, (unsigned long long*)(partials + (idx >> 4)));
        }
    }
}

// ---------------------------------------------------------------------------
// Pass B: scatter cache-resident partials into partitioned LDS stats.
// 8-edge unroll: 6 independent loads in flight per thread to hide L2/L3
// latency. 3 blocks/CU (24 waves). No global atomics.
// ---------------------------------------------------------------------------
__global__ void __launch_bounds__(SCAT_BLK, 6)
scatter_kernel(const int* __restrict__ dst, const float2* __restrict__ partials,
               float* __restrict__ acc, int nEdges) {
    __shared__ float sm[SLICE];
    const int tid = threadIdx.x;
    for (int i = tid; i < SLICE; i += SCAT_BLK) sm[i] = 0.0f;
    __syncthreads();

    const int p  = blockIdx.x / BPERP;
    const int b  = blockIdx.x % BPERP;
    const int lo = p * NPP;

    const int step = BPERP * SCAT_BLK * 8;       // 196608 edges per sweep
    for (int i0 = (b * SCAT_BLK + tid) * 8; i0 < nEdges; i0 += step) {
        if (i0 + 7 < nEdges) {
            int4   da = *(const int4*)(dst + i0);
            int4   db = *(const int4*)(dst + i0 + 4);
            float4 p0 = *(const float4*)(partials + i0);
            float4 p1 = *(const float4*)(partials + i0 + 2);
            float4 p2 = *(const float4*)(partials + i0 + 4);
            float4 p3 = *(const float4*)(partials + i0 + 6);
            EDGE_ACC(da.x, p0.x, p0.y); EDGE_ACC(da.y, p0.z, p0.w);
            EDGE_ACC(da.z, p1.x, p1.y); EDGE_ACC(da.w, p1.z, p1.w);
            EDGE_ACC(db.x, p2.x, p2.y); EDGE_ACC(db.y, p2.z, p2.w);
            EDGE_ACC(db.z, p3.x, p3.y); EDGE_ACC(db.w, p3.z, p3.w);
        } else {
            for (int i = i0; i < nEdges; ++i) {
                float2 pq = partials[i];
                EDGE_ACC(dst[i], pq.x, pq.y);
            }
        }
    }
    __syncthreads();
    float* __restrict__ outp = acc + (size_t)blockIdx.x * SLICE;
    for (int i = tid; i < SLICE; i += SCAT_BLK) {
        __builtin_nontemporal_store(sm[i], outp + i);   // no L3 pollution
    }
}

// ---------------------------------------------------------------------------
// Pass C: sum the BPERP per-block copies (nt loads: acc is dead after this,
// keep it out of L3 so e's tail survives for norm); mean + 1/(std+eps).
// ---------------------------------------------------------------------------
__global__ void __launch_bounds__(256)
reduce_finalize_kernel(const float* __restrict__ acc, float2* __restrict__ stats,
                       int nNodes) {
    int n = blockIdx.x * blockDim.x + threadIdx.x;
    if (n >= nNodes) return;
    int p = n / NPP, local = n - p * NPP;
    const float* bptr = acc + (size_t)(p * BPERP) * SLICE + local;
    float s = 0.f, q = 0.f, dg = 0.f;
#pragma unroll 8
    for (int bb = 0; bb < BPERP; ++bb, bptr += SLICE) {
        s  += __builtin_nontemporal_load(bptr);
        q  += __builtin_nontemporal_load(bptr + NPP);
        dg += __builtin_nontemporal_load(bptr + 2 * NPP);
    }
    float cnt  = dg * (float)FDIM;
    float safe = fmaxf(cnt, 1.0f);
    float mean = s / safe;
    float var  = (q - cnt * mean * mean) / fmaxf(cnt - 1.0f, 1.0f);
    float stdv = sqrtf(fmaxf(var, 0.0f));
    stats[n] = make_float2(mean, 1.0f / (stdv + EPS_C));
}

// ---------------------------------------------------------------------------
// Pass D: normalize. Reverse iteration order (read e's L3-resident tail
// first) + nt stores for out (keep out's 410 MB from evicting e in L3).
// ---------------------------------------------------------------------------
__global__ void __launch_bounds__(256)
norm_kernel(const float4* __restrict__ e4, const int* __restrict__ dst,
            const float2* __restrict__ stats,
            const float4* __restrict__ gamma4, const float4* __restrict__ beta4,
            float4* __restrict__ out4, int nEdges) {
    const int total  = nEdges * 16;
    const int stride = gridDim.x * blockDim.x;   // %16==0
    const int gtid   = blockIdx.x * blockDim.x + threadIdx.x;
    const int sub    = gtid & 15;
    const float4 g = gamma4[sub];
    const float4 b = beta4[sub];
    const int nIter = (total + stride - 1) / stride;
    for (int it = nIter - 1; it >= 0; --it) {
        int idx = it * stride + gtid;
        if (idx >= total) continue;
        float2 mi = stats[dst[idx >> 4]];
        float4 v  = e4[idx];
        nt_store_f4(out4 + idx,
                    g.x * (v.x - mi.x) * mi.y + b.x,
                    g.y * (v.y - mi.x) * mi.y + b.y,
                    g.z * (v.z - mi.x) * mi.y + b.z,
                    g.w * (v.w - mi.x) * mi.y + b.w);
    }
}

extern "C" void kernel_launch(void* const* d_in, const int* in_sizes, int n_in,
                              void* d_out, int out_size, void* d_ws, size_t ws_size,
                              hipStream_t stream) {
    const float* e     = (const float*)d_in[0];
    const float* gamma = (const float*)d_in[1];
    const float* beta  = (const float*)d_in[2];
    const int*   dst   = (const int*)d_in[3];
    const int nEdges = in_sizes[3];
    const int nNodes = N_NODES_C;

    // d_ws layout (all regions fully overwritten every call -> no memset):
    //   acc      [SCAT_GRID][SLICE] = 28.8 MB
    //   stats    [N] float2         =  0.4 MB
    //   partials [E] float2         = 12.8 MB
    float*  acc      = (float*)d_ws;
    float2* stats    = (float2*)(acc + (size_t)SCAT_GRID * SLICE);
    float2* partials = stats + nNodes;

    partial_kernel<<<2048, 256, 0, stream>>>((const float4*)e, partials, nEdges);
    scatter_kernel<<<SCAT_GRID, SCAT_BLK, 0, stream>>>(dst, partials, acc, nEdges);
    reduce_finalize_kernel<<<(nNodes + 255) / 256, 256, 0, stream>>>(acc, stats, nNodes);
    norm_kernel<<<2048, 256, 0, stream>>>(
        (const float4*)e, dst, stats,
        (const float4*)gamma, (const float4*)beta,
        (float4*)d_out, nEdges);
}